// Round 2
// baseline (1080.034 us; speedup 1.0000x reference)
//
#include <hip/hip_runtime.h>
#include <hip/hip_bf16.h>

// Problem constants
#define NPTS 256      // points per flat batch
#define NB   4        // flat batches (B*T)
#define KNN  27
#define EPSV 1e-5f

// All inputs/outputs are fp32 (reference dtype); threshold is 2% relative.
//
// Algebraic restructuring: graph feature is [neigh-center; center], so
//   h[b,o,n,k] = Wa.F[idx[n,k]] + (Wb-Wa).F[n]  with Wa=w[:, :Cf], Wb=w[:, Cf:]
// Precompute P = Wa.F and Q = (Wb-Wa).F  (two GEMMs, no K dim), then
//   max_k h = (sc>=0 ? max_k P[idx] : min_k P[idx]) + Q[n]
// and BN stats from the same gather pass. ~20x FLOP reduction vs naive.

// ---------------- workspace layout (bytes) ----------------
#define OFF_IDX   0           // 4*256*27*4      = 110592
#define OFF_XYZ   110592      // 4*3*256*4       = 12288
#define OFF_PQ    122880      // 4*6144*256*4    = 25165824
#define OFF_MX    25288704    // 4*3072*256*4    = 12582912
#define OFF_MN    37871616    // 4*3072*256*4    = 12582912
#define OFF_SUMS  50454528    // 2*3072*4        = 24576
#define OFF_XCAT  50479104    // 4*8160*256*4    = 33423360
#define OFF_Y     83902464    // 4*256*256*4     = 1048576
// total ~ 85 MB

// ---------------- kNN ----------------
// One wave (64 threads) per point. Key = (f32 bits of d)<<32 | j  (d>=0 so
// uint order == (d, j) lexicographic order, matching top_k stable ties).
__device__ __forceinline__ float dist3_nocontract(float ax, float ay, float az,
                                                  float bx, float by, float bz) {
#pragma clang fp contract(off)
    float dx = bx - ax, dy = by - ay, dz = bz - az;
    float s = dx * dx;
    s = s + dy * dy;
    s = s + dz * dz;
    return s;
}

__global__ __launch_bounds__(64) void knn_kernel(const float* __restrict__ x,
                                                 int* __restrict__ idx,
                                                 float* __restrict__ xyz) {
    int pt = blockIdx.x;            // 0..1023
    int b = pt >> 8, n = pt & 255;
    int lane = threadIdx.x;

    float xp0 = x[pt * 3 + 0];
    float xp1 = x[pt * 3 + 1];
    float xp2 = x[pt * 3 + 2];

    // also emit xyz in [b][c][n] fp32 layout for the layer-0 GEMM
    if (lane < 3) xyz[b * (3 * NPTS) + lane * NPTS + n] = x[pt * 3 + lane];

    unsigned long long key[4];
#pragma unroll
    for (int u = 0; u < 4; ++u) {
        int j = lane + 64 * u;
        int gj = b * NPTS + j;
        float cx = x[gj * 3 + 0];
        float cy = x[gj * 3 + 1];
        float cz = x[gj * 3 + 2];
        float d = dist3_nocontract(xp0, xp1, xp2, cx, cy, cz);
        key[u] = ((unsigned long long)__float_as_uint(d) << 32) | (unsigned int)j;
    }

    for (int r = 0; r < KNN; ++r) {
        unsigned long long m = key[0];
        m = key[1] < m ? key[1] : m;
        m = key[2] < m ? key[2] : m;
        m = key[3] < m ? key[3] : m;
#pragma unroll
        for (int off = 32; off; off >>= 1) {
            unsigned long long o = __shfl_xor(m, off);
            m = o < m ? o : m;
        }
        if (lane == 0) idx[pt * KNN + r] = (int)(m & 0xffffffffu);
#pragma unroll
        for (int u = 0; u < 4; ++u)
            if (key[u] == m) key[u] = ~0ULL;
    }
}

// ---------------- generic fp32 GEMM ----------------
// out[b][r][n] = sum_c A(r,c) * F_b[c][n]
// mode 0 (PQ): A(r,c) = r<Co ? w[r][c] : w[r-Co][Kd + c] - w[r-Co][c]
//              (w row stride 2*Kd; Kd = Cf)
// mode 1 (plain): A(r,c) = w[r][c] (row stride Kd), with optional split-K
//              (nsplit>1 -> atomicAdd into pre-zeroed out)
#define TM 64
#define TN 64
#define KT 16

__global__ __launch_bounds__(256) void gemm_kernel(const float* __restrict__ w,
                                                   const float* __restrict__ F,
                                                   float* __restrict__ out,
                                                   int M, int Co, int Kd,
                                                   long bsF, long bsO,
                                                   int mode, int nsplit) {
    __shared__ float As[KT][TM + 4];
    __shared__ float Bs[KT][TN + 4];

    int bz = blockIdx.z;
    int b = bz / nsplit, slice = bz % nsplit;
    int kchunk = (Kd + nsplit - 1) / nsplit;
    kchunk = ((kchunk + KT - 1) / KT) * KT;
    int kstart = slice * kchunk;
    int kend = Kd < (kstart + kchunk) ? Kd : (kstart + kchunk);

    const float* Fb = F + (long)b * bsF;
    float* Ob = out + (long)b * bsO;

    int m0 = blockIdx.x * TM, n0 = blockIdx.y * TN;
    int tid = threadIdx.x;
    int tx = tid & 15, ty = tid >> 4;

    float acc[4][4] = {};

    int am = tid >> 2;        // 0..63 (row within tile)
    int ak = (tid & 3) * 4;   // 0,4,8,12
    int bn = tid & 63;
    int bk0 = tid >> 6;       // 0..3

    for (int kk = kstart; kk < kend; kk += KT) {
        int r = m0 + am;
#pragma unroll
        for (int j = 0; j < 4; ++j) {
            int c = kk + ak + j;
            float a = 0.f;
            if (r < M && c < kend) {
                if (mode == 0) {
                    if (r < Co) {
                        a = w[(long)r * (2 * Kd) + c];
                    } else {
                        long base = (long)(r - Co) * (2 * Kd);
                        a = w[base + Kd + c] - w[base + c];
                    }
                } else {
                    a = w[(long)r * Kd + c];
                }
            }
            As[ak + j][am] = a;
        }
#pragma unroll
        for (int j = 0; j < 4; ++j) {
            int k = bk0 + j * 4;
            int c = kk + k;
            Bs[k][bn] = (c < kend) ? Fb[(long)c * NPTS + n0 + bn] : 0.f;
        }
        __syncthreads();
#pragma unroll
        for (int k = 0; k < KT; ++k) {
            float av[4], bv[4];
#pragma unroll
            for (int i = 0; i < 4; ++i) av[i] = As[k][ty * 4 + i];
#pragma unroll
            for (int j = 0; j < 4; ++j) bv[j] = Bs[k][tx * 4 + j];
#pragma unroll
            for (int i = 0; i < 4; ++i)
#pragma unroll
                for (int j = 0; j < 4; ++j) acc[i][j] += av[i] * bv[j];
        }
        __syncthreads();
    }

#pragma unroll
    for (int i = 0; i < 4; ++i) {
        int r = m0 + ty * 4 + i;
        if (r < M) {
            float* po = Ob + (long)r * NPTS + n0 + tx * 4;
            if (nsplit == 1) {
#pragma unroll
                for (int j = 0; j < 4; ++j) po[j] = acc[i][j];
            } else {
#pragma unroll
                for (int j = 0; j < 4; ++j) atomicAdd(po + j, acc[i][j]);
            }
        }
    }
}

// ---------------- neighbor gather + per-channel stats ----------------
// Block = 256 threads = 4 waves; block handles channel o for all 4 batches.
// h[b,o,n,k] = P[b,o,idx[b,n,k]] + Q[b,o,n].
// Emits per-(b,o,n) max/min of h and per-channel (sum, sumsq) over b,n,k.
__global__ __launch_bounds__(256) void neigh_stats(const float* __restrict__ PQ,
                                                   const int* __restrict__ idx,
                                                   float* __restrict__ MX,
                                                   float* __restrict__ MN,
                                                   float* __restrict__ sums,
                                                   int Co) {
    __shared__ float p_sh[NB][NPTS];
    __shared__ float red[8];
    int o = blockIdx.x;
    int b = threadIdx.x >> 6;
    int lane = threadIdx.x & 63;

    const float* Prow = PQ + ((long)b * 2 * Co + o) * NPTS;
    const float* Qrow = PQ + ((long)b * 2 * Co + Co + o) * NPTS;

#pragma unroll
    for (int u = 0; u < 4; ++u) p_sh[b][lane + 64 * u] = Prow[lane + 64 * u];
    __syncthreads();

    float s = 0.f, ss = 0.f;
#pragma unroll
    for (int u = 0; u < 4; ++u) {
        int n = lane + 64 * u;
        float q = Qrow[n];
        const int* ip = idx + ((long)b * NPTS + n) * KNN;
        float mx = -__builtin_inff(), mn = __builtin_inff();
#pragma unroll
        for (int k = 0; k < KNN; ++k) {
            float h = p_sh[b][ip[k]] + q;
            s += h;
            ss += h * h;
            mx = fmaxf(mx, h);
            mn = fminf(mn, h);
        }
        MX[((long)b * Co + o) * NPTS + n] = mx;
        MN[((long)b * Co + o) * NPTS + n] = mn;
    }
#pragma unroll
    for (int off = 32; off; off >>= 1) {
        s += __shfl_xor(s, off);
        ss += __shfl_xor(ss, off);
    }
    if (lane == 0) {
        red[b] = s;
        red[4 + b] = ss;
    }
    __syncthreads();
    if (threadIdx.x == 0) {
        float ts = (red[0] + red[1]) + (red[2] + red[3]);
        float tss = (red[4] + red[5]) + (red[6] + red[7]);
        sums[o] = ts;
        sums[Co + o] = tss;
    }
}

// ---------------- BN + lrelu + temporal-pool concat ----------------
// val[b,o,n] = lrelu(sc*(extreme h) + tt);  extreme = max if sc>=0 else min
// (lrelu(affine(.)) is monotone with direction sign(sc), so max over k
//  commutes with the pointwise ops).
// xcat[b][offc+o][n]      = val[b]
// xcat[b][offc+Co+o][n]   = 0.5*(val[0]+val[1])   (reference's tp quirk: batch
//                           index 0 of shape (B,T,...) -> flat batches 0,1)
__global__ __launch_bounds__(256) void finalize_comb(const float* __restrict__ MX,
                                                     const float* __restrict__ MN,
                                                     const float* __restrict__ sums,
                                                     const float* __restrict__ g,
                                                     const float* __restrict__ beta,
                                                     float* __restrict__ xcat,
                                                     int Co, int offc) {
    int o = blockIdx.x;
    int n = threadIdx.x;
    const float cnt = (float)(NB * NPTS * KNN);
    float mean = sums[o] / cnt;
    float var = sums[Co + o] / cnt - mean * mean;
    float sc = g[o] * (1.0f / sqrtf(var + EPSV));
    float tt = beta[o] - mean * sc;

    float val[4];
#pragma unroll
    for (int b = 0; b < 4; ++b) {
        float v = (sc >= 0.f) ? MX[((long)b * Co + o) * NPTS + n]
                              : MN[((long)b * Co + o) * NPTS + n];
        float z = sc * v + tt;
        val[b] = z >= 0.f ? z : 0.2f * z;
    }
    float tp = 0.5f * (val[0] + val[1]);
#pragma unroll
    for (int b = 0; b < 4; ++b) {
        xcat[(long)b * 8160 * NPTS + (long)(offc + o) * NPTS + n] = val[b];
        xcat[(long)b * 8160 * NPTS + (long)(offc + Co + o) * NPTS + n] = tp;
    }
}

// ---------------- final BN + lrelu -> fp32 out ----------------
// One block per output channel o (LATENT=256). Stats over (4 batches x 256 n).
__global__ __launch_bounds__(256) void final_bn(const float* __restrict__ y,
                                                const float* __restrict__ g4,
                                                const float* __restrict__ b4,
                                                float* __restrict__ out) {
    __shared__ float red[8];
    int o = blockIdx.x;
    int tid = threadIdx.x;
    int lane = tid & 63, w = tid >> 6;

    float v[4];
    float s = 0.f, ss = 0.f;
#pragma unroll
    for (int b = 0; b < 4; ++b) {
        v[b] = y[(long)b * 65536 + o * 256 + tid];
        s += v[b];
        ss += v[b] * v[b];
    }
#pragma unroll
    for (int off = 32; off; off >>= 1) {
        s += __shfl_xor(s, off);
        ss += __shfl_xor(ss, off);
    }
    if (lane == 0) {
        red[w] = s;
        red[4 + w] = ss;
    }
    __syncthreads();
    s = (red[0] + red[1]) + (red[2] + red[3]);
    ss = (red[4] + red[5]) + (red[6] + red[7]);
    float mean = s / 1024.f;
    float var = ss / 1024.f - mean * mean;
    float sc = g4[o] * (1.0f / sqrtf(var + EPSV));
    float tt = b4[o] - mean * sc;
#pragma unroll
    for (int b = 0; b < 4; ++b) {
        float z = sc * v[b] + tt;
        z = z >= 0.f ? z : 0.2f * z;
        out[(long)b * 65536 + o * 256 + tid] = z;
    }
}

// ---------------- launch ----------------
extern "C" void kernel_launch(void* const* d_in, const int* in_sizes, int n_in,
                              void* d_out, int out_size, void* d_ws, size_t ws_size,
                              hipStream_t stream) {
    const float* x = (const float*)d_in[0];
    const float* wl[4];
    const float* gl[4];
    const float* bl[4];
    for (int i = 0; i < 4; ++i) {
        wl[i] = (const float*)d_in[1 + 3 * i];
        gl[i] = (const float*)d_in[2 + 3 * i];
        bl[i] = (const float*)d_in[3 + 3 * i];
    }
    const float* w4 = (const float*)d_in[13];
    const float* g4 = (const float*)d_in[14];
    const float* b4 = (const float*)d_in[15];

    char* ws = (char*)d_ws;
    int* idx = (int*)(ws + OFF_IDX);
    float* xyz = (float*)(ws + OFF_XYZ);
    float* PQ = (float*)(ws + OFF_PQ);
    float* MX = (float*)(ws + OFF_MX);
    float* MN = (float*)(ws + OFF_MN);
    float* sums = (float*)(ws + OFF_SUMS);
    float* xcat = (float*)(ws + OFF_XCAT);
    float* y = (float*)(ws + OFF_Y);

    // kNN (+ xyz transpose)
    knn_kernel<<<dim3(NB * NPTS), dim3(64), 0, stream>>>(x, idx, xyz);

    const int Cf[4] = {3, 96, 384, 1536};
    const int Co[4] = {48, 192, 768, 3072};
    const int offc[4] = {0, 96, 480, 2016};
    const int inoff[4] = {0, 0, 96, 480};

    for (int i = 0; i < 4; ++i) {
        const float* F;
        long bsF;
        if (i == 0) {
            F = xyz;
            bsF = 3 * NPTS;
        } else {
            F = xcat + (long)inoff[i] * NPTS;
            bsF = (long)8160 * NPTS;
        }
        int M = 2 * Co[i];
        dim3 grid((M + TM - 1) / TM, NPTS / TN, NB);
        gemm_kernel<<<grid, dim3(256), 0, stream>>>(wl[i], F, PQ, M, Co[i], Cf[i],
                                                    bsF, (long)M * NPTS, 0, 1);
        neigh_stats<<<dim3(Co[i]), dim3(256), 0, stream>>>(PQ, idx, MX, MN, sums, Co[i]);
        finalize_comb<<<dim3(Co[i]), dim3(256), 0, stream>>>(MX, MN, sums, gl[i], bl[i],
                                                             xcat, Co[i], offc[i]);
    }

    // final projection: y[b][o][n], split-K=4 with atomic accumulation
    hipMemsetAsync(y, 0, (size_t)NB * 256 * 256 * 4, stream);
    {
        int nsplit = 4;
        dim3 grid((256 + TM - 1) / TM, NPTS / TN, NB * nsplit);
        gemm_kernel<<<grid, dim3(256), 0, stream>>>(w4, xcat, y, 256, 0, 8160,
                                                    (long)8160 * NPTS, (long)256 * NPTS,
                                                    1, nsplit);
    }
    final_bn<<<dim3(256), dim3(256), 0, stream>>>(y, g4, b4, (float*)d_out);
}

// Round 3
// 393.825 us; speedup vs baseline: 2.7424x; 2.7424x over previous
//
#include <hip/hip_runtime.h>
#include <hip/hip_bf16.h>

#define NPTS 256
#define NB   4
#define KNN  27
#define EPSV 1e-5f

// ---------------- workspace layout (bytes), total 84.93 MB (<= proven 85 MB) ----
#define OFF_IDX    0           // 4*256*27*4          = 110592
#define OFF_XYZT   110592      // 4*256*4*4           = 16384   fp32 [b][n][4]
#define OFF_PQ     126976      // 4*6144*256*4        = 25165824
#define OFF_SLICE  25292800    // 4*6144*256*4        = 25165824 (current layer comb, [b][2Co][n])
#define OFF_XCATT  50458624    // 4*256*8160*4        = 33423360 fp32 [b][n][8160]
#define OFF_Y      83881984    // 4*256*256*4         = 1048576

typedef __attribute__((ext_vector_type(8))) short bf16x8;
typedef __attribute__((ext_vector_type(4))) float f32x4;

__device__ __forceinline__ unsigned short bf16_rne(float a) {
    unsigned int u = __float_as_uint(a);
    return (unsigned short)((u + 0x7fffu + ((u >> 16) & 1u)) >> 16);
}

// ---------------- kNN ----------------
__device__ __forceinline__ float dist3_nocontract(float ax, float ay, float az,
                                                  float bx, float by, float bz) {
#pragma clang fp contract(off)
    float dx = bx - ax, dy = by - ay, dz = bz - az;
    float s = dx * dx;
    s = s + dy * dy;
    s = s + dz * dz;
    return s;
}

__global__ __launch_bounds__(64) void knn_kernel(const float* __restrict__ x,
                                                 int* __restrict__ idx,
                                                 float* __restrict__ xyzT) {
    int pt = blockIdx.x;            // 0..1023
    int b = pt >> 8, n = pt & 255;
    int lane = threadIdx.x;

    float xp0 = x[pt * 3 + 0];
    float xp1 = x[pt * 3 + 1];
    float xp2 = x[pt * 3 + 2];

    // xyzT fp32 [b][n][4] (k-contiguous rows for the GEMM B-operand; col 3 never read)
    if (lane < 3) xyzT[((long)b * NPTS + n) * 4 + lane] = x[pt * 3 + lane];

    unsigned long long key[4];
#pragma unroll
    for (int u = 0; u < 4; ++u) {
        int j = lane + 64 * u;
        int gj = b * NPTS + j;
        float d = dist3_nocontract(xp0, xp1, xp2,
                                   x[gj * 3 + 0], x[gj * 3 + 1], x[gj * 3 + 2]);
        key[u] = ((unsigned long long)__float_as_uint(d) << 32) | (unsigned int)j;
    }

    for (int r = 0; r < KNN; ++r) {
        unsigned long long m = key[0];
        m = key[1] < m ? key[1] : m;
        m = key[2] < m ? key[2] : m;
        m = key[3] < m ? key[3] : m;
#pragma unroll
        for (int off = 32; off; off >>= 1) {
            unsigned long long o = __shfl_xor(m, off);
            m = o < m ? o : m;
        }
        if (lane == 0) idx[pt * KNN + r] = (int)(m & 0xffffffffu);
#pragma unroll
        for (int u = 0; u < 4; ++u)
            if (key[u] == m) key[u] = ~0ULL;
    }
}

// ---------------- split-bf16 MFMA GEMM ----------------
// out[b][r][n] = sum_c A(r,c) * F[c][n], fp32-accurate via hi/lo bf16 split:
//   a*f ~= ah*fh + ah*fl + al*fh   (residual ~2^-17 relative)
// A source (mode 0): r<Co -> w[r][c]; else w[r-Co][K+c]-w[r-Co][c] (w stride 2K)
// A source (mode 1): w[r][c] (stride K), optional split-K with atomicAdd.
// F source: FT fp32 [n][k] rows (k-contiguous), row stride ldF.
// Block: 256 thr, tile BM=64 x BN=64, BK=32; 4 waves in 2x2; per wave 2x2
// mfma_f32_16x16x32_bf16 tiles x 3 products.
__global__ __launch_bounds__(256) void gemm_mfma(
    const float* __restrict__ w, const float* __restrict__ FT,
    float* __restrict__ out, int M, int Co, int K,
    int ldF, long bsF, long bsO, int mode, int nsplit)
{
    __shared__ unsigned short As_hi[64][40], As_lo[64][40];   // [m][k], 80 B rows (16B-aligned segs)
    __shared__ unsigned short Bs_hi[64][40], Bs_lo[64][40];   // [n][k]

    int bz = blockIdx.z;
    int b = bz / nsplit, slice = bz - b * nsplit;
    int kchunk = (((K + nsplit - 1) / nsplit) + 31) & ~31;
    int kstart = slice * kchunk;
    int kend = K < kstart + kchunk ? K : kstart + kchunk;

    const float* Fb = FT + (long)b * bsF;
    float* Ob = out + (long)b * bsO;

    int m0 = blockIdx.x * 64, n0 = blockIdx.y * 64;
    int tid = threadIdx.x;
    int lane = tid & 63;
    int wid = tid >> 6;
    int wm = (wid >> 1) * 32, wn = (wid & 1) * 32;
    int lrow = lane & 15, quad = lane >> 4;

    int srow = tid >> 2;          // 0..63
    int sseg = (tid & 3) * 8;     // 0,8,16,24

    f32x4 acc[2][2] = {};

    for (int kk = kstart; kk < kend; kk += 32) {
        bool full = (kk + 32 <= kend);
        float a[8];

        // ---- stage A (with weight transform + hi/lo split)
        {
            int R = m0 + srow;
#pragma unroll
            for (int j = 0; j < 8; ++j) a[j] = 0.f;
            if (R < M) {
                if (mode == 1) {
                    const float* p = w + (long)R * K + kk + sseg;
                    if (full) {
                        f32x4 v0 = *(const f32x4*)p;
                        f32x4 v1 = *(const f32x4*)(p + 4);
#pragma unroll
                        for (int j = 0; j < 4; ++j) { a[j] = v0[j]; a[4 + j] = v1[j]; }
                    } else {
#pragma unroll
                        for (int j = 0; j < 8; ++j)
                            if (kk + sseg + j < kend) a[j] = p[j];
                    }
                } else if (R < Co) {
                    const float* p = w + (long)R * (2 * K) + kk + sseg;
                    if (full) {
                        f32x4 v0 = *(const f32x4*)p;
                        f32x4 v1 = *(const f32x4*)(p + 4);
#pragma unroll
                        for (int j = 0; j < 4; ++j) { a[j] = v0[j]; a[4 + j] = v1[j]; }
                    } else {
#pragma unroll
                        for (int j = 0; j < 8; ++j)
                            if (kk + sseg + j < kend) a[j] = p[j];
                    }
                } else {
                    const float* p0 = w + (long)(R - Co) * (2 * K) + kk + sseg;
                    const float* p1 = p0 + K;
                    if (full) {
                        f32x4 u0 = *(const f32x4*)p1;
                        f32x4 u1 = *(const f32x4*)(p1 + 4);
                        f32x4 v0 = *(const f32x4*)p0;
                        f32x4 v1 = *(const f32x4*)(p0 + 4);
#pragma unroll
                        for (int j = 0; j < 4; ++j) { a[j] = u0[j] - v0[j]; a[4 + j] = u1[j] - v1[j]; }
                    } else {
#pragma unroll
                        for (int j = 0; j < 8; ++j)
                            if (kk + sseg + j < kend) a[j] = p1[j] - p0[j];
                    }
                }
            }
            bf16x8 hv, lv;
#pragma unroll
            for (int j = 0; j < 8; ++j) {
                unsigned short h = bf16_rne(a[j]);
                float ah = __uint_as_float((unsigned int)h << 16);
                unsigned short l = bf16_rne(a[j] - ah);
                hv[j] = (short)h;
                lv[j] = (short)l;
            }
            *(bf16x8*)&As_hi[srow][sseg] = hv;
            *(bf16x8*)&As_lo[srow][sseg] = lv;
        }

        // ---- stage B (feature rows, hi/lo split)
        {
            const float* p = Fb + (long)(n0 + srow) * ldF + kk + sseg;
#pragma unroll
            for (int j = 0; j < 8; ++j) a[j] = 0.f;
            if (full) {
                f32x4 v0 = *(const f32x4*)p;
                f32x4 v1 = *(const f32x4*)(p + 4);
#pragma unroll
                for (int j = 0; j < 4; ++j) { a[j] = v0[j]; a[4 + j] = v1[j]; }
            } else {
#pragma unroll
                for (int j = 0; j < 8; ++j)
                    if (kk + sseg + j < kend) a[j] = p[j];
            }
            bf16x8 hv, lv;
#pragma unroll
            for (int j = 0; j < 8; ++j) {
                unsigned short h = bf16_rne(a[j]);
                float ah = __uint_as_float((unsigned int)h << 16);
                unsigned short l = bf16_rne(a[j] - ah);
                hv[j] = (short)h;
                lv[j] = (short)l;
            }
            *(bf16x8*)&Bs_hi[srow][sseg] = hv;
            *(bf16x8*)&Bs_lo[srow][sseg] = lv;
        }

        __syncthreads();

        bf16x8 ah[2], al[2], bh[2], bl[2];
#pragma unroll
        for (int t = 0; t < 2; ++t) {
            ah[t] = *(const bf16x8*)&As_hi[wm + t * 16 + lrow][quad * 8];
            al[t] = *(const bf16x8*)&As_lo[wm + t * 16 + lrow][quad * 8];
            bh[t] = *(const bf16x8*)&Bs_hi[wn + t * 16 + lrow][quad * 8];
            bl[t] = *(const bf16x8*)&Bs_lo[wn + t * 16 + lrow][quad * 8];
        }
#pragma unroll
        for (int mt = 0; mt < 2; ++mt)
#pragma unroll
            for (int nt = 0; nt < 2; ++nt)
                acc[mt][nt] = __builtin_amdgcn_mfma_f32_16x16x32_bf16(ah[mt], bh[nt], acc[mt][nt], 0, 0, 0);
#pragma unroll
        for (int mt = 0; mt < 2; ++mt)
#pragma unroll
            for (int nt = 0; nt < 2; ++nt)
                acc[mt][nt] = __builtin_amdgcn_mfma_f32_16x16x32_bf16(ah[mt], bl[nt], acc[mt][nt], 0, 0, 0);
#pragma unroll
        for (int mt = 0; mt < 2; ++mt)
#pragma unroll
            for (int nt = 0; nt < 2; ++nt)
                acc[mt][nt] = __builtin_amdgcn_mfma_f32_16x16x32_bf16(al[mt], bh[nt], acc[mt][nt], 0, 0, 0);

        __syncthreads();
    }

    // epilogue: C/D layout col=lane&15, row=quad*4+reg  [m89-verified]
#pragma unroll
    for (int mt = 0; mt < 2; ++mt)
#pragma unroll
        for (int nt = 0; nt < 2; ++nt) {
            int C = n0 + wn + nt * 16 + lrow;
            int Rb = m0 + wm + mt * 16 + quad * 4;
#pragma unroll
            for (int r = 0; r < 4; ++r) {
                int R = Rb + r;
                if (R < M) {
                    float* po = Ob + (long)R * NPTS + C;
                    if (nsplit == 1) *po = acc[mt][nt][r];
                    else atomicAdd(po, acc[mt][nt][r]);
                }
            }
        }
}

// ---------------- fused neighbor gather + stats + BN/lrelu + tp concat -------
// Block = channel o; h[b,o,n,k] = P[b,o,idx[b,n,k]] + Q[b,o,n].
// Phase 1: per-(b,n) max/min (regs) + channel sum/sumsq (block reduce).
// Phase 2: sc/tt, val = lrelu(sc*extreme+tt), tp = 0.5*(val[flat0]+val[flat1]),
// write slice[b][o][n] and slice[b][Co+o][n].
__global__ __launch_bounds__(256) void gather_finalize(
    const float* __restrict__ PQ, const int* __restrict__ idx,
    const float* __restrict__ g, const float* __restrict__ beta,
    float* __restrict__ slice, int Co)
{
    __shared__ float p_sh[NB][NPTS];
    __shared__ float val_sh[NB][NPTS];
    __shared__ float red[8];
    int o = blockIdx.x;
    int b = threadIdx.x >> 6;
    int lane = threadIdx.x & 63;

    const float* Prow = PQ + ((long)b * 2 * Co + o) * NPTS;
    const float* Qrow = PQ + ((long)b * 2 * Co + Co + o) * NPTS;

#pragma unroll
    for (int u = 0; u < 4; ++u) p_sh[b][lane + 64 * u] = Prow[lane + 64 * u];
    __syncthreads();

    float mx[4], mn[4];
    float s = 0.f, ss = 0.f;
#pragma unroll
    for (int u = 0; u < 4; ++u) {
        int n = lane + 64 * u;
        float q = Qrow[n];
        const int* ip = idx + ((long)b * NPTS + n) * KNN;
        float vmx = -__builtin_inff(), vmn = __builtin_inff();
#pragma unroll
        for (int k = 0; k < KNN; ++k) {
            float h = p_sh[b][ip[k]] + q;
            s += h;
            ss += h * h;
            vmx = fmaxf(vmx, h);
            vmn = fminf(vmn, h);
        }
        mx[u] = vmx;
        mn[u] = vmn;
    }
#pragma unroll
    for (int off = 32; off; off >>= 1) {
        s += __shfl_xor(s, off);
        ss += __shfl_xor(ss, off);
    }
    if (lane == 0) { red[b] = s; red[4 + b] = ss; }
    __syncthreads();

    float ts = (red[0] + red[1]) + (red[2] + red[3]);
    float tss = (red[4] + red[5]) + (red[6] + red[7]);
    const float cnt = (float)(NB * NPTS * KNN);
    float mean = ts / cnt;
    float var = tss / cnt - mean * mean;
    float sc = g[o] * (1.0f / sqrtf(var + EPSV));
    float tt = beta[o] - mean * sc;

#pragma unroll
    for (int u = 0; u < 4; ++u) {
        int n = lane + 64 * u;
        float v = (sc >= 0.f) ? mx[u] : mn[u];
        float z = sc * v + tt;
        val_sh[b][n] = z >= 0.f ? z : 0.2f * z;
    }
    __syncthreads();

#pragma unroll
    for (int u = 0; u < 4; ++u) {
        int n = lane + 64 * u;
        float tp = 0.5f * (val_sh[0][n] + val_sh[1][n]);
        slice[((long)b * 2 * Co + o) * NPTS + n] = val_sh[b][n];
        slice[((long)b * 2 * Co + Co + o) * NPTS + n] = tp;
    }
}

// ---------------- transpose [b][C][n] -> xcatT [b][n][8160] (at offc) -------
__global__ __launch_bounds__(256) void transpose_cn(
    const float* __restrict__ slice, float* __restrict__ xcatT,
    int Ctot, int offc)
{
    __shared__ float t[32][33];
    int c0 = blockIdx.x * 32, n0 = blockIdx.y * 32, b = blockIdx.z;
    const float* S = slice + (long)b * Ctot * NPTS;
    int tid = threadIdx.x;
    int r = tid >> 3, s4 = (tid & 7) * 4;

    f32x4 v = *(const f32x4*)&S[(long)(c0 + r) * NPTS + n0 + s4];
    t[r][s4 + 0] = v[0];
    t[r][s4 + 1] = v[1];
    t[r][s4 + 2] = v[2];
    t[r][s4 + 3] = v[3];
    __syncthreads();

    float* D = xcatT + ((long)b * NPTS + n0 + r) * 8160 + offc + c0 + s4;
    f32x4 o;
    o[0] = t[s4 + 0][r];
    o[1] = t[s4 + 1][r];
    o[2] = t[s4 + 2][r];
    o[3] = t[s4 + 3][r];
    *(f32x4*)D = o;
}

// ---------------- final BN + lrelu -> fp32 out ----------------
__global__ __launch_bounds__(256) void final_bn(const float* __restrict__ y,
                                                const float* __restrict__ g4,
                                                const float* __restrict__ b4,
                                                float* __restrict__ out) {
    __shared__ float red[8];
    int o = blockIdx.x;
    int tid = threadIdx.x;
    int lane = tid & 63, w = tid >> 6;

    float v[4];
    float s = 0.f, ss = 0.f;
#pragma unroll
    for (int b = 0; b < 4; ++b) {
        v[b] = y[(long)b * 65536 + o * 256 + tid];
        s += v[b];
        ss += v[b] * v[b];
    }
#pragma unroll
    for (int off = 32; off; off >>= 1) {
        s += __shfl_xor(s, off);
        ss += __shfl_xor(ss, off);
    }
    if (lane == 0) { red[w] = s; red[4 + w] = ss; }
    __syncthreads();
    s = (red[0] + red[1]) + (red[2] + red[3]);
    ss = (red[4] + red[5]) + (red[6] + red[7]);
    float mean = s / 1024.f;
    float var = ss / 1024.f - mean * mean;
    float sc = g4[o] * (1.0f / sqrtf(var + EPSV));
    float tt = b4[o] - mean * sc;
#pragma unroll
    for (int b = 0; b < 4; ++b) {
        float z = sc * v[b] + tt;
        z = z >= 0.f ? z : 0.2f * z;
        out[(long)b * 65536 + o * 256 + tid] = z;
    }
}

// ---------------- launch ----------------
extern "C" void kernel_launch(void* const* d_in, const int* in_sizes, int n_in,
                              void* d_out, int out_size, void* d_ws, size_t ws_size,
                              hipStream_t stream) {
    const float* x = (const float*)d_in[0];
    const float* wl[4];
    const float* gl[4];
    const float* bl[4];
    for (int i = 0; i < 4; ++i) {
        wl[i] = (const float*)d_in[1 + 3 * i];
        gl[i] = (const float*)d_in[2 + 3 * i];
        bl[i] = (const float*)d_in[3 + 3 * i];
    }
    const float* w4 = (const float*)d_in[13];
    const float* g4 = (const float*)d_in[14];
    const float* b4 = (const float*)d_in[15];

    char* ws = (char*)d_ws;
    int* idx = (int*)(ws + OFF_IDX);
    float* xyzT = (float*)(ws + OFF_XYZT);
    float* PQ = (float*)(ws + OFF_PQ);
    float* slice = (float*)(ws + OFF_SLICE);
    float* xcatT = (float*)(ws + OFF_XCATT);
    float* y = (float*)(ws + OFF_Y);

    knn_kernel<<<dim3(NB * NPTS), dim3(64), 0, stream>>>(x, idx, xyzT);

    const int Cf[4] = {3, 96, 384, 1536};
    const int Co[4] = {48, 192, 768, 3072};
    const int offc[4] = {0, 96, 480, 2016};
    const int inoff[4] = {0, 0, 96, 480};

    for (int i = 0; i < 4; ++i) {
        const float* FB;
        int ldF;
        long bsF;
        if (i == 0) {
            FB = xyzT; ldF = 4; bsF = (long)NPTS * 4;
        } else {
            FB = xcatT + inoff[i]; ldF = 8160; bsF = (long)NPTS * 8160;
        }
        int M = 2 * Co[i];
        dim3 grid((M + 63) / 64, NPTS / 64, NB);
        gemm_mfma<<<grid, dim3(256), 0, stream>>>(wl[i], FB, PQ, M, Co[i], Cf[i],
                                                  ldF, bsF, (long)M * NPTS, 0, 1);
        gather_finalize<<<dim3(Co[i]), dim3(256), 0, stream>>>(PQ, idx, gl[i], bl[i],
                                                               slice, Co[i]);
        transpose_cn<<<dim3(M / 32, NPTS / 32, NB), dim3(256), 0, stream>>>(slice, xcatT,
                                                                            M, offc[i]);
    }

    // final projection with split-K=8 (atomic accumulate into zeroed y)
    hipMemsetAsync(y, 0, (size_t)NB * 256 * 256 * 4, stream);
    gemm_mfma<<<dim3(4, 4, NB * 8), dim3(256), 0, stream>>>(w4, xcatT, y, 256, 0, 8160,
                                                            8160, (long)NPTS * 8160,
                                                            (long)256 * NPTS, 1, 8);
    final_bn<<<dim3(256), dim3(256), 0, stream>>>(y, g4, b4, (float*)d_out);
}